// Round 3
// baseline (31291.617 us; speedup 1.0000x reference)
//
#include <hip/hip_runtime.h>
#include <math.h>

#define D 256
#define SEQ 1000
#define NB 32
#define PATCH 160
#define NL 6
#define M_TOTAL (NB * SEQ)   // 32000
#define G3 (3 * D)           // 768

__device__ __forceinline__ float gelu_exact(float v) {
    return 0.5f * v * (1.0f + erff(v * 0.70710678118654752440f));
}

// Raw workgroup barrier: orders LDS (lgkmcnt) but does NOT drain vmcnt, so
// in-flight global stores (publish, x-writeback) and prefetch loads cross
// phases without stalling. Compiler still inserts vmcnt waits at value uses.
__device__ __forceinline__ void bar_lds() {
    asm volatile("s_waitcnt lgkmcnt(0)" ::: "memory");
    __builtin_amdgcn_s_barrier();
    asm volatile("" ::: "memory");
}

// ---------------------------------------------------------------------------
// Kernel 1: conv patchify GEMM + exact GELU + pos_emb add
// ---------------------------------------------------------------------------
__global__ __launch_bounds__(256) void conv_gelu_pos(
    const float* __restrict__ wav, const float* __restrict__ cw,
    const float* __restrict__ pos, float* __restrict__ x)
{
    __shared__ float As[64][33];
    __shared__ float Bs[32][65];
    const int m0 = blockIdx.x * 64;
    const int n0 = blockIdx.y * 64;
    const int tid = threadIdx.x;
    const int tx = tid & 15;      // 0..15 -> n
    const int ty = tid >> 4;      // 0..15 -> m
    float acc[4][4] = {};

    for (int kc = 0; kc < PATCH; kc += 32) {
        for (int p = 0; p < 8; ++p) {
            int mr = p * 8 + (tid >> 5);
            int kk = tid & 31;
            int m = m0 + mr;
            int b = m / SEQ, s = m % SEQ;
            As[mr][kk] = wav[(size_t)b * 160000 + (size_t)s * PATCH + kc + kk];
        }
        for (int p = 0; p < 8; ++p) {
            int kr = p * 4 + (tid >> 6);
            int nn = tid & 63;
            Bs[kr][nn] = cw[(size_t)(kc + kr) * D + n0 + nn];
        }
        __syncthreads();
        #pragma unroll
        for (int kk = 0; kk < 32; ++kk) {
            float a[4], bb[4];
            #pragma unroll
            for (int i = 0; i < 4; ++i) a[i] = As[ty * 4 + i][kk];
            #pragma unroll
            for (int j = 0; j < 4; ++j) bb[j] = Bs[kk][tx * 4 + j];
            #pragma unroll
            for (int i = 0; i < 4; ++i)
                #pragma unroll
                for (int j = 0; j < 4; ++j)
                    acc[i][j] = fmaf(a[i], bb[j], acc[i][j]);
        }
        __syncthreads();
    }
    #pragma unroll
    for (int i = 0; i < 4; ++i) {
        int m = m0 + ty * 4 + i;
        int s = m % SEQ;
        int n = n0 + tx * 4;
        float4 v;
        v.x = gelu_exact(acc[i][0]) + pos[(size_t)s * D + n + 0];
        v.y = gelu_exact(acc[i][1]) + pos[(size_t)s * D + n + 1];
        v.z = gelu_exact(acc[i][2]) + pos[(size_t)s * D + n + 2];
        v.w = gelu_exact(acc[i][3]) + pos[(size_t)s * D + n + 3];
        *(float4*)&x[(size_t)m * D + n] = v;
    }
}

// ---------------------------------------------------------------------------
// Kernel 2: per-row mean / rstd (LayerNorm stats). One wave per row.
// ---------------------------------------------------------------------------
__global__ __launch_bounds__(64) void row_stats(
    const float* __restrict__ x, float* __restrict__ st)
{
    const int m = blockIdx.x;
    const int t = threadIdx.x;
    const float* r = x + (size_t)m * D;
    float s = 0.f, q = 0.f;
    #pragma unroll
    for (int i = 0; i < 4; ++i) {
        float v = r[t + 64 * i];
        s += v;
        q += v * v;
    }
    #pragma unroll
    for (int o = 32; o > 0; o >>= 1) {
        s += __shfl_down(s, o);
        q += __shfl_down(q, o);
    }
    if (t == 0) {
        float mu = s * (1.f / 256.f);
        float var = q * (1.f / 256.f) - mu * mu;
        st[2 * m]     = mu;
        st[2 * m + 1] = rsqrtf(var + 1e-5f);
    }
}

// ---------------------------------------------------------------------------
// Kernel 3: fused LN + input-projection GEMM
// ---------------------------------------------------------------------------
__global__ __launch_bounds__(256) void ln_xp_gemm(
    const float* __restrict__ x, const float* __restrict__ st,
    const float* __restrict__ lnsc, const float* __restrict__ lnbi,
    const float* __restrict__ wih, const float* __restrict__ bih,
    float* __restrict__ xp)
{
    __shared__ float As[64][33];
    __shared__ float Bs[32][65];
    __shared__ float sc[D], bi[D];
    const int m0 = blockIdx.x * 64;
    const int n0 = blockIdx.y * 64;
    const int tid = threadIdx.x;
    const int tx = tid & 15;
    const int ty = tid >> 4;
    sc[tid] = lnsc[tid];
    bi[tid] = lnbi[tid];
    float acc[4][4] = {};

    for (int kc = 0; kc < D; kc += 32) {
        for (int p = 0; p < 8; ++p) {
            int mr = p * 8 + (tid >> 5);
            int kk = tid & 31;
            int m = m0 + mr;
            float mu = st[2 * m], rs = st[2 * m + 1];
            float v = x[(size_t)m * D + kc + kk];
            As[mr][kk] = (v - mu) * rs * sc[kc + kk] + bi[kc + kk];
        }
        for (int p = 0; p < 8; ++p) {
            int nr = p * 8 + (tid >> 5);
            int kk = tid & 31;
            Bs[kk][nr] = wih[(size_t)(n0 + nr) * D + kc + kk];
        }
        __syncthreads();
        #pragma unroll
        for (int kk = 0; kk < 32; ++kk) {
            float a[4], bb[4];
            #pragma unroll
            for (int i = 0; i < 4; ++i) a[i] = As[ty * 4 + i][kk];
            #pragma unroll
            for (int j = 0; j < 4; ++j) bb[j] = Bs[kk][tx * 4 + j];
            #pragma unroll
            for (int i = 0; i < 4; ++i)
                #pragma unroll
                for (int j = 0; j < 4; ++j)
                    acc[i][j] = fmaf(a[i], bb[j], acc[i][j]);
        }
        __syncthreads();
    }
    #pragma unroll
    for (int i = 0; i < 4; ++i) {
        int m = m0 + ty * 4 + i;
        int n = n0 + tx * 4;
        float4 v;
        v.x = acc[i][0] + bih[n + 0];
        v.y = acc[i][1] + bih[n + 1];
        v.z = acc[i][2] + bih[n + 2];
        v.w = acc[i][3] + bih[n + 3];
        *(float4*)&xp[(size_t)m * G3 + n] = v;
    }
}

// ---------------------------------------------------------------------------
// Kernel 4: transpose w_hh [768][256] -> whT [256][768]
// ---------------------------------------------------------------------------
__global__ __launch_bounds__(256) void transpose_whh(
    const float* __restrict__ whh, float* __restrict__ whT)
{
    __shared__ float t[32][33];
    const int g0 = blockIdx.x * 32;
    const int k0 = blockIdx.y * 32;
    const int lx = threadIdx.x & 31;
    const int ly = threadIdx.x >> 5;   // 0..7
    for (int i = 0; i < 32; i += 8)
        t[ly + i][lx] = whh[(size_t)(g0 + ly + i) * D + k0 + lx];
    __syncthreads();
    for (int i = 0; i < 32; i += 8)
        whT[(size_t)(k0 + ly + i) * G3 + g0 + lx] = t[lx][ly + i];
}

// ---------------------------------------------------------------------------
// Kernel 4b: zero the exchange buffer (once per launch). Needed: a previous
// launch leaves tokens {base+999, base+1000} in the slots, which WOULD be
// false-accepted when this launch reaches the same (layer,step).
// ---------------------------------------------------------------------------
__global__ __launch_bounds__(256) void zero_exch(unsigned long long* __restrict__ e)
{
    e[blockIdx.x * 256 + threadIdx.x] = 0ull;
}

// ---------------------------------------------------------------------------
// Kernel 5: GRU recurrence, register-resident weights, output-split pair,
// 4-batch round-robin pipeline.
//
// Round-2 post-mortem: exchange one-way (HBM write-through + L3 load) is
// ~2500-3000cy and was serially exposed every step; __syncthreads after the
// publish additionally drained the store to HBM ack. Fixes:
//   - Each block pair time-multiplexes FOUR batches over the SAME resident
//     weights (weights are batch-invariant). Batch p's publish->pickup gets a
//     ~3-phase (~3500cy) transit window: latency fully hidden.
//   - Per phase, all global loads (next batch's pickup, this batch's xp/xold)
//     issue BEFORE the 768cy FMA block and are consumed after it.
//   - Phase barriers are raw s_barrier + lgkmcnt(0) only (bar_lds): publish
//     and x-writeback stores stay in flight across phases (no vmcnt drain).
// Protocol per batch is identical to round 2 (proven): packed u64
// token|payload, relaxed agent scope, parity double-buffer, exact-token
// match. Same induction => no overwrite race, no deadlock, bitwise-identical
// h across the pair.
// Phase structure (phase p of iteration u, q=(p+1)&3):
//   1. issue: kq1 -> pickup load for batch q (h-step sq = p==3 ? u+1 : u,
//      published >=3 phases ago); kq0 -> xp/xold for batch p, step u.
//   2. FMA batch p over h_lds[p] (full 256-wide h).
//   3. partial-sum stores; bar_lds.
//   4. kq0: combine (fixed order) + gates + publish h(u+1) + h_lds/x update;
//      kq1: token-check pickup value (re-poll on miss), write h_lds[q] peer
//      half. bar_lds.
// ---------------------------------------------------------------------------
__global__ __launch_bounds__(512, 2) void gru_scan_quad(
    const float* __restrict__ xp, const float* __restrict__ whT,
    const float* __restrict__ bhh, float* __restrict__ x,
    unsigned long long* exch, int layer)
{
    __shared__ float h_lds[4][D];         // per-batch h(t)
    __shared__ float pr[3][3][128];       // [kq-1][gate][dd] partial sums
    const int tid  = threadIdx.x;
    const int kq   = tid >> 7;            // 0..3 (wave-uniform)
    const int dd   = tid & 127;
    const int grp  = blockIdx.x >> 1;     // 0..7, group of 4 batches
    const int half = blockIdx.x & 1;      // output-dim half
    const int dout = half * 128 + dd;
    const int k0   = kq * 64;

    // --- resident weights: gates r,z,n of dout, K quarter = 192 floats -----
    float wr[64], wz[64], wn[64];
    {
        const float* wb = whT + (size_t)k0 * G3 + dout;
        #pragma unroll
        for (int k = 0; k < 64; ++k) {
            wr[k] = wb[(size_t)k * G3];
            wz[k] = wb[(size_t)k * G3 + D];
            wn[k] = wb[(size_t)k * G3 + 2 * D];
        }
    }
    const float bh_r = bhh[dout];
    const float bh_z = bhh[D + dout];
    const float bh_n = bhh[2 * D + dout];

    for (int i = tid; i < 4 * D; i += 512) ((float*)h_lds)[i] = 0.f;
    __syncthreads();

    const unsigned int base = (unsigned int)layer * SEQ;  // token(s) = base+s

    for (int u = 0; u < SEQ; ++u) {
        #pragma unroll
        for (int p = 0; p < 4; ++p) {
            const int q  = (p + 1) & 3;
            const int sq = (p == 3) ? u + 1 : u;     // pickup h-step for q
            const int bp = grp * 4 + p;              // global batch this phase
            const int bq = grp * 4 + q;
            const bool do_pick = (kq == 1) && (sq >= 1) && (sq <= SEQ - 1);

            // ---- step 1: issue all global loads ---------------------------
            unsigned long long pk = 0;
            const unsigned long long* pick_addr =
                exch + ((size_t)(bq * 2 + (1 - half)) * 2 + (sq & 1)) * 128 + dd;
            if (do_pick)
                pk = __hip_atomic_load(pick_addr, __ATOMIC_RELAXED,
                                       __HIP_MEMORY_SCOPE_AGENT);
            float xr = 0.f, xz = 0.f, xn_ = 0.f, xold = 0.f;
            if (kq == 0) {
                const float* xpt = xp + ((size_t)bp * SEQ + u) * G3;
                xr   = xpt[dout];
                xz   = xpt[D + dout];
                xn_  = xpt[2 * D + dout];
                xold = x[((size_t)bp * SEQ + u) * D + dout];
            }

            // ---- step 2: FMA over h_lds[p] (latency-hiding body) ----------
            float ar = 0.f, az = 0.f, an = 0.f;
            #pragma unroll
            for (int qq = 0; qq < 16; ++qq) {
                float4 hv = *(const float4*)&h_lds[p][k0 + qq * 4];
                ar = fmaf(hv.x, wr[4*qq+0], ar); az = fmaf(hv.x, wz[4*qq+0], az); an = fmaf(hv.x, wn[4*qq+0], an);
                ar = fmaf(hv.y, wr[4*qq+1], ar); az = fmaf(hv.y, wz[4*qq+1], az); an = fmaf(hv.y, wn[4*qq+1], an);
                ar = fmaf(hv.z, wr[4*qq+2], ar); az = fmaf(hv.z, wz[4*qq+2], az); an = fmaf(hv.z, wn[4*qq+2], an);
                ar = fmaf(hv.w, wr[4*qq+3], ar); az = fmaf(hv.w, wz[4*qq+3], az); an = fmaf(hv.w, wn[4*qq+3], an);
            }

            // ---- step 3: reduce partials ----------------------------------
            if (kq) { pr[kq-1][0][dd] = ar; pr[kq-1][1][dd] = az; pr[kq-1][2][dd] = an; }
            bar_lds();

            // ---- step 4: finalize batch p; consume pickup for batch q -----
            if (kq == 0) {
                ar += pr[0][0][dd] + pr[1][0][dd] + pr[2][0][dd];
                az += pr[0][1][dd] + pr[1][1][dd] + pr[2][1][dd];
                an += pr[0][2][dd] + pr[1][2][dd] + pr[2][2][dd];
                float r = 1.f / (1.f + expf(-(xr + ar + bh_r)));
                float z = 1.f / (1.f + expf(-(xz + az + bh_z)));
                float n = tanhf(xn_ + r * (an + bh_n));
                float hnew = (1.f - z) * n + z * h_lds[p][dout];
                unsigned long long w =
                    ((unsigned long long)(base + u + 1) << 32) |
                    (unsigned long long)__float_as_uint(hnew);
                __hip_atomic_store(
                    exch + ((size_t)(bp * 2 + half) * 2 + ((u + 1) & 1)) * 128 + dd,
                    w, __ATOMIC_RELAXED, __HIP_MEMORY_SCOPE_AGENT);
                h_lds[p][dout] = hnew;
                x[((size_t)bp * SEQ + u) * D + dout] = xold + hnew;
            } else if (do_pick) {
                const unsigned int want = base + (unsigned int)sq;
                unsigned long long w = pk;
                if ((unsigned int)(w >> 32) != want) {
                    do {
                        w = __hip_atomic_load(pick_addr, __ATOMIC_RELAXED,
                                              __HIP_MEMORY_SCOPE_AGENT);
                    } while ((unsigned int)(w >> 32) != want);
                }
                h_lds[q][(1 - half) * 128 + dd] =
                    __uint_as_float((unsigned int)w);
            }
            bar_lds();
        }
    }
}

// ---------------------------------------------------------------------------
// Kernel 6: final LN + mean-pool over sequence
// ---------------------------------------------------------------------------
__global__ __launch_bounds__(256) void pool_ln(
    const float* __restrict__ x, const float* __restrict__ st,
    const float* __restrict__ fsc, const float* __restrict__ fbi,
    float* __restrict__ emb)
{
    const int b = blockIdx.x;
    const int d = threadIdx.x;
    float acc = 0.f;
    for (int s = 0; s < SEQ; ++s) {
        int m = b * SEQ + s;
        acc += (x[(size_t)m * D + d] - st[2 * m]) * st[2 * m + 1];
    }
    emb[b * D + d] = (acc * (1.f / (float)SEQ)) * fsc[d] + fbi[d];
}

// ---------------------------------------------------------------------------
// Kernel 7: classification head (tiny). Single block.
// ---------------------------------------------------------------------------
__global__ __launch_bounds__(256) void head_mlp(
    const float* __restrict__ emb, const float* __restrict__ w1,
    const float* __restrict__ b1, const float* __restrict__ w2,
    const float* __restrict__ b2, float* __restrict__ out)
{
    __shared__ float es[NB][D + 1];
    __shared__ float h1[NB][128 + 1];
    const int t = threadIdx.x;
    for (int i = t; i < NB * D; i += 256) es[i / D][i % D] = emb[i];
    __syncthreads();
    for (int i = t; i < NB * 128; i += 256) {
        int bb = i / 128, j = i % 128;
        float a = b1[j];
        for (int k = 0; k < D; ++k) a = fmaf(es[bb][k], w1[(size_t)k * 128 + j], a);
        h1[bb][j] = gelu_exact(a);
    }
    __syncthreads();
    for (int i = t; i < NB * 8; i += 256) {
        int bb = i / 8, c = i % 8;
        float a = b2[c];
        for (int k = 0; k < 128; ++k) a = fmaf(h1[bb][k], w2[(size_t)k * 8 + c], a);
        out[i] = a;
    }
}

// ---------------------------------------------------------------------------
extern "C" void kernel_launch(void* const* d_in, const int* in_sizes, int n_in,
                              void* d_out, int out_size, void* d_ws, size_t ws_size,
                              hipStream_t stream)
{
    const float* wav  = (const float*)d_in[0];
    const float* cw   = (const float*)d_in[1];
    const float* pos  = (const float*)d_in[2];
    const float* lnsc = (const float*)d_in[3];
    const float* lnbi = (const float*)d_in[4];
    const float* wih  = (const float*)d_in[5];
    const float* whh  = (const float*)d_in[6];
    const float* bih  = (const float*)d_in[7];
    const float* bhh  = (const float*)d_in[8];
    const float* fsc  = (const float*)d_in[9];
    const float* fbi  = (const float*)d_in[10];
    const float* hw1  = (const float*)d_in[11];
    const float* hb1  = (const float*)d_in[12];
    const float* hw2  = (const float*)d_in[13];
    const float* hb2  = (const float*)d_in[14];

    float* ws    = (float*)d_ws;
    float* x     = ws;                        // 8,192,000 f
    float* xp    = x + (size_t)M_TOTAL * D;   // 24,576,000 f
    float* st    = xp + (size_t)M_TOTAL * G3; // 64,000 f
    float* whT   = st + 2 * M_TOTAL;          // 196,608 f
    float* emb   = whT + D * G3;              // 8,192 f
    unsigned long long* exch = (unsigned long long*)(emb + NB * D); // 64*2*128 u64

    zero_exch<<<64, 256, 0, stream>>>(exch);  // 16384 u64
    conv_gelu_pos<<<dim3(M_TOTAL / 64, D / 64), 256, 0, stream>>>(wav, cw, pos, x);

    for (int l = 0; l < NL; ++l) {
        row_stats<<<M_TOTAL, 64, 0, stream>>>(x, st);
        ln_xp_gemm<<<dim3(M_TOTAL / 64, G3 / 64), 256, 0, stream>>>(
            x, st, lnsc + (size_t)l * D, lnbi + (size_t)l * D,
            wih + (size_t)l * G3 * D, bih + (size_t)l * G3, xp);
        transpose_whh<<<dim3(G3 / 32, D / 32), 256, 0, stream>>>(
            whh + (size_t)l * G3 * D, whT);
        gru_scan_quad<<<16, 512, 0, stream>>>(
            xp, whT, bhh + (size_t)l * G3, x, exch, l);
    }

    row_stats<<<M_TOTAL, 64, 0, stream>>>(x, st);
    pool_ln<<<NB, D, 0, stream>>>(x, st, fsc, fbi, emb);
    head_mlp<<<1, 256, 0, stream>>>(emb, hw1, hb1, hw2, hb2, (float*)d_out);
}

// Round 6
// 12076.527 us; speedup vs baseline: 2.5911x; 2.5911x over previous
//
#include <hip/hip_runtime.h>
#include <math.h>

#define D 256
#define SEQ 1000
#define NB 32
#define PATCH 160
#define NL 6
#define M_TOTAL (NB * SEQ)   // 32000
#define G3 (3 * D)           // 768

__device__ __forceinline__ float gelu_exact(float v) {
    return 0.5f * v * (1.0f + erff(v * 0.70710678118654752440f));
}

// Raw workgroup barrier: orders LDS (lgkmcnt) but does NOT drain vmcnt, so
// in-flight global stores (publish, x-writeback) cross steps without
// stalling. The exchange protocol's correctness comes from the packed
// token|payload match, not from barrier-ordered visibility; same-thread
// same-address store ordering keeps the slot-reuse induction intact.
// (This barrier passed harness verification inside the round-3 kernel.)
__device__ __forceinline__ void bar_lds() {
    asm volatile("s_waitcnt lgkmcnt(0)" ::: "memory");
    __builtin_amdgcn_s_barrier();
    asm volatile("" ::: "memory");
}

// ---------------------------------------------------------------------------
// Kernel 1: conv patchify GEMM + exact GELU + pos_emb add
// ---------------------------------------------------------------------------
__global__ __launch_bounds__(256) void conv_gelu_pos(
    const float* __restrict__ wav, const float* __restrict__ cw,
    const float* __restrict__ pos, float* __restrict__ x)
{
    __shared__ float As[64][33];
    __shared__ float Bs[32][65];
    const int m0 = blockIdx.x * 64;
    const int n0 = blockIdx.y * 64;
    const int tid = threadIdx.x;
    const int tx = tid & 15;      // 0..15 -> n
    const int ty = tid >> 4;      // 0..15 -> m
    float acc[4][4] = {};

    for (int kc = 0; kc < PATCH; kc += 32) {
        for (int p = 0; p < 8; ++p) {
            int mr = p * 8 + (tid >> 5);
            int kk = tid & 31;
            int m = m0 + mr;
            int b = m / SEQ, s = m % SEQ;
            As[mr][kk] = wav[(size_t)b * 160000 + (size_t)s * PATCH + kc + kk];
        }
        for (int p = 0; p < 8; ++p) {
            int kr = p * 4 + (tid >> 6);
            int nn = tid & 63;
            Bs[kr][nn] = cw[(size_t)(kc + kr) * D + n0 + nn];
        }
        __syncthreads();
        #pragma unroll
        for (int kk = 0; kk < 32; ++kk) {
            float a[4], bb[4];
            #pragma unroll
            for (int i = 0; i < 4; ++i) a[i] = As[ty * 4 + i][kk];
            #pragma unroll
            for (int j = 0; j < 4; ++j) bb[j] = Bs[kk][tx * 4 + j];
            #pragma unroll
            for (int i = 0; i < 4; ++i)
                #pragma unroll
                for (int j = 0; j < 4; ++j)
                    acc[i][j] = fmaf(a[i], bb[j], acc[i][j]);
        }
        __syncthreads();
    }
    #pragma unroll
    for (int i = 0; i < 4; ++i) {
        int m = m0 + ty * 4 + i;
        int s = m % SEQ;
        int n = n0 + tx * 4;
        float4 v;
        v.x = gelu_exact(acc[i][0]) + pos[(size_t)s * D + n + 0];
        v.y = gelu_exact(acc[i][1]) + pos[(size_t)s * D + n + 1];
        v.z = gelu_exact(acc[i][2]) + pos[(size_t)s * D + n + 2];
        v.w = gelu_exact(acc[i][3]) + pos[(size_t)s * D + n + 3];
        *(float4*)&x[(size_t)m * D + n] = v;
    }
}

// ---------------------------------------------------------------------------
// Kernel 2: per-row mean / rstd (LayerNorm stats). One wave per row.
// ---------------------------------------------------------------------------
__global__ __launch_bounds__(64) void row_stats(
    const float* __restrict__ x, float* __restrict__ st)
{
    const int m = blockIdx.x;
    const int t = threadIdx.x;
    const float* r = x + (size_t)m * D;
    float s = 0.f, q = 0.f;
    #pragma unroll
    for (int i = 0; i < 4; ++i) {
        float v = r[t + 64 * i];
        s += v;
        q += v * v;
    }
    #pragma unroll
    for (int o = 32; o > 0; o >>= 1) {
        s += __shfl_down(s, o);
        q += __shfl_down(q, o);
    }
    if (t == 0) {
        float mu = s * (1.f / 256.f);
        float var = q * (1.f / 256.f) - mu * mu;
        st[2 * m]     = mu;
        st[2 * m + 1] = rsqrtf(var + 1e-5f);
    }
}

// ---------------------------------------------------------------------------
// Kernel 3: fused LN + input-projection GEMM
// ---------------------------------------------------------------------------
__global__ __launch_bounds__(256) void ln_xp_gemm(
    const float* __restrict__ x, const float* __restrict__ st,
    const float* __restrict__ lnsc, const float* __restrict__ lnbi,
    const float* __restrict__ wih, const float* __restrict__ bih,
    float* __restrict__ xp)
{
    __shared__ float As[64][33];
    __shared__ float Bs[32][65];
    __shared__ float sc[D], bi[D];
    const int m0 = blockIdx.x * 64;
    const int n0 = blockIdx.y * 64;
    const int tid = threadIdx.x;
    const int tx = tid & 15;
    const int ty = tid >> 4;
    sc[tid] = lnsc[tid];
    bi[tid] = lnbi[tid];
    float acc[4][4] = {};

    for (int kc = 0; kc < D; kc += 32) {
        for (int p = 0; p < 8; ++p) {
            int mr = p * 8 + (tid >> 5);
            int kk = tid & 31;
            int m = m0 + mr;
            float mu = st[2 * m], rs = st[2 * m + 1];
            float v = x[(size_t)m * D + kc + kk];
            As[mr][kk] = (v - mu) * rs * sc[kc + kk] + bi[kc + kk];
        }
        for (int p = 0; p < 8; ++p) {
            int nr = p * 8 + (tid >> 5);
            int kk = tid & 31;
            Bs[kk][nr] = wih[(size_t)(n0 + nr) * D + kc + kk];
        }
        __syncthreads();
        #pragma unroll
        for (int kk = 0; kk < 32; ++kk) {
            float a[4], bb[4];
            #pragma unroll
            for (int i = 0; i < 4; ++i) a[i] = As[ty * 4 + i][kk];
            #pragma unroll
            for (int j = 0; j < 4; ++j) bb[j] = Bs[kk][tx * 4 + j];
            #pragma unroll
            for (int i = 0; i < 4; ++i)
                #pragma unroll
                for (int j = 0; j < 4; ++j)
                    acc[i][j] = fmaf(a[i], bb[j], acc[i][j]);
        }
        __syncthreads();
    }
    #pragma unroll
    for (int i = 0; i < 4; ++i) {
        int m = m0 + ty * 4 + i;
        int n = n0 + tx * 4;
        float4 v;
        v.x = acc[i][0] + bih[n + 0];
        v.y = acc[i][1] + bih[n + 1];
        v.z = acc[i][2] + bih[n + 2];
        v.w = acc[i][3] + bih[n + 3];
        *(float4*)&xp[(size_t)m * G3 + n] = v;
    }
}

// ---------------------------------------------------------------------------
// Kernel 4: transpose w_hh [768][256] -> whT [256][768]
// ---------------------------------------------------------------------------
__global__ __launch_bounds__(256) void transpose_whh(
    const float* __restrict__ whh, float* __restrict__ whT)
{
    __shared__ float t[32][33];
    const int g0 = blockIdx.x * 32;
    const int k0 = blockIdx.y * 32;
    const int lx = threadIdx.x & 31;
    const int ly = threadIdx.x >> 5;   // 0..7
    for (int i = 0; i < 32; i += 8)
        t[ly + i][lx] = whh[(size_t)(g0 + ly + i) * D + k0 + lx];
    __syncthreads();
    for (int i = 0; i < 32; i += 8)
        whT[(size_t)(k0 + ly + i) * G3 + g0 + lx] = t[lx][ly + i];
}

// ---------------------------------------------------------------------------
// Kernel 4b: zero the exchange buffer (once per launch). Tokens are exact-
// matched per (layer,step), so a zeroed buffer can never alias a live token.
// ---------------------------------------------------------------------------
__global__ __launch_bounds__(256) void zero_exch(unsigned long long* __restrict__ e)
{
    e[blockIdx.x * 256 + threadIdx.x] = 0ull;
}

// ---------------------------------------------------------------------------
// Kernel 5: GRU recurrence, register-resident weights, OUTPUT-dim split pair.
//
// Rounds 4-5 post-mortem: both same-XCD fast-path variants hung -> the
// same-XCD premise (XCC_ID readback / %8 round-robin) is not verifiable on
// this harness; the mechanism is banned. This is the PROVEN round-2 protocol
// (agent-scope relaxed atomics, packed u64 token|payload, parity slots,
// exact-token match -> race-free by induction, bitwise-identical h across
// the pair) with one measured-safe change: bar_lds instead of __syncthreads
// inside the step loop. Round-2's __syncthreads drained vmcnt(0) every step,
// serially waiting for the publish + x-writeback stores to reach agent
// visibility (~0.5-1.4k cy); bar_lds (lgkmcnt-only) removes that drain.
// Correctness does not depend on the drain: the poller accepts a slot only
// on token match, and slot reuse at t+2 happens-after the peer consumed t
// (same-thread same-address stores remain ordered without vmcnt drains).
// ---------------------------------------------------------------------------
__global__ __launch_bounds__(512, 2) void gru_scan_pair(
    const float* __restrict__ xp, const float* __restrict__ whT,
    const float* __restrict__ bhh, float* __restrict__ x,
    unsigned long long* exch, int layer)
{
    __shared__ float h_lds[D];            // full h(t): own half + peer half
    __shared__ float pr[3][3][128];       // [kq-1][gate][dd] partial sums
    const int tid  = threadIdx.x;
    const int kq   = tid >> 7;            // 0..3 (wave-uniform: 2 waves/kq)
    const int dd   = tid & 127;
    const int pair = blockIdx.x >> 1;     // batch index
    const int half = blockIdx.x & 1;      // output-dim half
    const int dout = half * 128 + dd;
    const int k0   = kq * 64;

    // --- resident weights: gates r,z,n of dout, K quarter = 192 floats -----
    float wr[64], wz[64], wn[64];
    {
        const float* wb = whT + (size_t)k0 * G3 + dout;
        #pragma unroll
        for (int k = 0; k < 64; ++k) {
            wr[k] = wb[(size_t)k * G3];
            wz[k] = wb[(size_t)k * G3 + D];
            wn[k] = wb[(size_t)k * G3 + 2 * D];
        }
    }
    const float bh_r = bhh[dout];
    const float bh_z = bhh[D + dout];
    const float bh_n = bhh[2 * D + dout];

    unsigned long long*       pub = exch + (size_t)(pair * 2 + half)       * 2 * 128;
    const unsigned long long* sub = exch + (size_t)(pair * 2 + (1 - half)) * 2 * 128;

    const float* xpb = xp + (size_t)pair * SEQ * G3;
    float* xb = x + (size_t)pair * SEQ * D;

    if (tid < D) h_lds[tid] = 0.f;
    __syncthreads();

    const unsigned int tok0 = (unsigned int)layer * SEQ + 1u;
    for (int t = 0; t < SEQ; ++t) {
        const unsigned int token = tok0 + (unsigned int)t;
        const int par = t & 1;

        // issue xp + residual loads early; latency hides under the FMA phase
        float xr = 0.f, xz = 0.f, xn_ = 0.f, xold = 0.f;
        if (kq == 0) {
            const float* xpt = xpb + (size_t)t * G3;
            xr   = xpt[dout];
            xz   = xpt[D + dout];
            xn_  = xpt[2 * D + dout];
            xold = xb[(size_t)t * D + dout];
        }

        // --- FMA phase: 192 FMAs against resident weights ------------------
        float ar = 0.f, az = 0.f, an = 0.f;
        #pragma unroll
        for (int q = 0; q < 16; ++q) {
            float4 hv = *(const float4*)&h_lds[k0 + q * 4];  // uniform bcast
            ar = fmaf(hv.x, wr[4*q+0], ar); az = fmaf(hv.x, wz[4*q+0], az); an = fmaf(hv.x, wn[4*q+0], an);
            ar = fmaf(hv.y, wr[4*q+1], ar); az = fmaf(hv.y, wz[4*q+1], az); an = fmaf(hv.y, wn[4*q+1], an);
            ar = fmaf(hv.z, wr[4*q+2], ar); az = fmaf(hv.z, wz[4*q+2], az); an = fmaf(hv.z, wn[4*q+2], an);
            ar = fmaf(hv.w, wr[4*q+3], ar); az = fmaf(hv.w, wz[4*q+3], az); an = fmaf(hv.w, wn[4*q+3], an);
        }
        if (kq) { pr[kq-1][0][dd] = ar; pr[kq-1][1][dd] = az; pr[kq-1][2][dd] = an; }
        bar_lds();

        if (kq == 0) {
            // combine K quarters in fixed order 0,1,2,3 (deterministic)
            ar += pr[0][0][dd] + pr[1][0][dd] + pr[2][0][dd];
            az += pr[0][1][dd] + pr[1][1][dd] + pr[2][1][dd];
            an += pr[0][2][dd] + pr[1][2][dd] + pr[2][2][dd];
            float r = 1.f / (1.f + expf(-(xr + ar + bh_r)));
            float z = 1.f / (1.f + expf(-(xz + az + bh_z)));
            float n = tanhf(xn_ + r * (an + bh_n));
            float hnew = (1.f - z) * n + z * h_lds[dout];
            // publish FIRST (peer's pickup is the critical path), then local
            unsigned long long w =
                ((unsigned long long)token << 32) | (unsigned long long)__float_as_uint(hnew);
            __hip_atomic_store(&pub[par * 128 + dd], w,
                               __ATOMIC_RELAXED, __HIP_MEMORY_SCOPE_AGENT);
            h_lds[dout] = hnew;
            xb[(size_t)t * D + dout] = xold + hnew;
        } else if (kq == 1) {
            // poller group: pick up peer's 128 h words for this step
            // (runs concurrently with kq0's combine/gates above)
            const unsigned long long* qw = &sub[par * 128 + dd];
            unsigned long long w;
            do {
                w = __hip_atomic_load(qw, __ATOMIC_RELAXED, __HIP_MEMORY_SCOPE_AGENT);
            } while ((unsigned int)(w >> 32) != token);
            h_lds[(1 - half) * 128 + dd] = __uint_as_float((unsigned int)w);
        }
        bar_lds();
    }
}

// ---------------------------------------------------------------------------
// Kernel 6: final LN + mean-pool over sequence
// ---------------------------------------------------------------------------
__global__ __launch_bounds__(256) void pool_ln(
    const float* __restrict__ x, const float* __restrict__ st,
    const float* __restrict__ fsc, const float* __restrict__ fbi,
    float* __restrict__ emb)
{
    const int b = blockIdx.x;
    const int d = threadIdx.x;
    float acc = 0.f;
    for (int s = 0; s < SEQ; ++s) {
        int m = b * SEQ + s;
        acc += (x[(size_t)m * D + d] - st[2 * m]) * st[2 * m + 1];
    }
    emb[b * D + d] = (acc * (1.f / (float)SEQ)) * fsc[d] + fbi[d];
}

// ---------------------------------------------------------------------------
// Kernel 7: classification head (tiny). Single block.
// ---------------------------------------------------------------------------
__global__ __launch_bounds__(256) void head_mlp(
    const float* __restrict__ emb, const float* __restrict__ w1,
    const float* __restrict__ b1, const float* __restrict__ w2,
    const float* __restrict__ b2, float* __restrict__ out)
{
    __shared__ float es[NB][D + 1];
    __shared__ float h1[NB][128 + 1];
    const int t = threadIdx.x;
    for (int i = t; i < NB * D; i += 256) es[i / D][i % D] = emb[i];
    __syncthreads();
    for (int i = t; i < NB * 128; i += 256) {
        int bb = i / 128, j = i % 128;
        float a = b1[j];
        for (int k = 0; k < D; ++k) a = fmaf(es[bb][k], w1[(size_t)k * 128 + j], a);
        h1[bb][j] = gelu_exact(a);
    }
    __syncthreads();
    for (int i = t; i < NB * 8; i += 256) {
        int bb = i / 8, c = i % 8;
        float a = b2[c];
        for (int k = 0; k < 128; ++k) a = fmaf(h1[bb][k], w2[(size_t)k * 8 + c], a);
        out[i] = a;
    }
}

// ---------------------------------------------------------------------------
extern "C" void kernel_launch(void* const* d_in, const int* in_sizes, int n_in,
                              void* d_out, int out_size, void* d_ws, size_t ws_size,
                              hipStream_t stream)
{
    const float* wav  = (const float*)d_in[0];
    const float* cw   = (const float*)d_in[1];
    const float* pos  = (const float*)d_in[2];
    const float* lnsc = (const float*)d_in[3];
    const float* lnbi = (const float*)d_in[4];
    const float* wih  = (const float*)d_in[5];
    const float* whh  = (const float*)d_in[6];
    const float* bih  = (const float*)d_in[7];
    const float* bhh  = (const float*)d_in[8];
    const float* fsc  = (const float*)d_in[9];
    const float* fbi  = (const float*)d_in[10];
    const float* hw1  = (const float*)d_in[11];
    const float* hb1  = (const float*)d_in[12];
    const float* hw2  = (const float*)d_in[13];
    const float* hb2  = (const float*)d_in[14];

    float* ws    = (float*)d_ws;
    float* x     = ws;                        // 8,192,000 f
    float* xp    = x + (size_t)M_TOTAL * D;   // 24,576,000 f
    float* st    = xp + (size_t)M_TOTAL * G3; // 64,000 f
    float* whT   = st + 2 * M_TOTAL;          // 196,608 f
    float* emb   = whT + D * G3;              // 8,192 f
    unsigned long long* exch = (unsigned long long*)(emb + NB * D); // 64*2*128 u64

    zero_exch<<<64, 256, 0, stream>>>(exch);  // 16384 u64
    conv_gelu_pos<<<dim3(M_TOTAL / 64, D / 64), 256, 0, stream>>>(wav, cw, pos, x);

    for (int l = 0; l < NL; ++l) {
        row_stats<<<M_TOTAL, 64, 0, stream>>>(x, st);
        ln_xp_gemm<<<dim3(M_TOTAL / 64, G3 / 64), 256, 0, stream>>>(
            x, st, lnsc + (size_t)l * D, lnbi + (size_t)l * D,
            wih + (size_t)l * G3 * D, bih + (size_t)l * G3, xp);
        transpose_whh<<<dim3(G3 / 32, D / 32), 256, 0, stream>>>(
            whh + (size_t)l * G3 * D, whT);
        gru_scan_pair<<<NB * 2, 512, 0, stream>>>(
            xp, whT, bhh + (size_t)l * G3, x, exch, l);
    }

    row_stats<<<M_TOTAL, 64, 0, stream>>>(x, st);
    pool_ln<<<NB, D, 0, stream>>>(x, st, fsc, fbi, emb);
    head_mlp<<<1, 256, 0, stream>>>(emb, hw1, hb1, hw2, hb2, (float*)d_out);
}

// Round 7
// 11221.563 us; speedup vs baseline: 2.7885x; 1.0762x over previous
//
#include <hip/hip_runtime.h>
#include <math.h>

#define D 256
#define SEQ 1000
#define NB 32
#define PATCH 160
#define NL 6
#define M_TOTAL (NB * SEQ)   // 32000
#define G3 (3 * D)           // 768

__device__ __forceinline__ float gelu_exact(float v) {
    return 0.5f * v * (1.0f + erff(v * 0.70710678118654752440f));
}

// Raw workgroup barrier: orders LDS (lgkmcnt) but does NOT drain vmcnt, so
// in-flight global stores (publish, x-writeback) cross steps without
// stalling. Exchange correctness comes from the packed token|payload match,
// not barrier-ordered visibility. (Harness-verified in rounds 3 and 6.)
__device__ __forceinline__ void bar_lds() {
    asm volatile("s_waitcnt lgkmcnt(0)" ::: "memory");
    __builtin_amdgcn_s_barrier();
    asm volatile("" ::: "memory");
}

// ---------------------------------------------------------------------------
// Kernel 1: conv patchify GEMM + exact GELU + pos_emb add
// ---------------------------------------------------------------------------
__global__ __launch_bounds__(256) void conv_gelu_pos(
    const float* __restrict__ wav, const float* __restrict__ cw,
    const float* __restrict__ pos, float* __restrict__ x)
{
    __shared__ float As[64][33];
    __shared__ float Bs[32][65];
    const int m0 = blockIdx.x * 64;
    const int n0 = blockIdx.y * 64;
    const int tid = threadIdx.x;
    const int tx = tid & 15;      // 0..15 -> n
    const int ty = tid >> 4;      // 0..15 -> m
    float acc[4][4] = {};

    for (int kc = 0; kc < PATCH; kc += 32) {
        for (int p = 0; p < 8; ++p) {
            int mr = p * 8 + (tid >> 5);
            int kk = tid & 31;
            int m = m0 + mr;
            int b = m / SEQ, s = m % SEQ;
            As[mr][kk] = wav[(size_t)b * 160000 + (size_t)s * PATCH + kc + kk];
        }
        for (int p = 0; p < 8; ++p) {
            int kr = p * 4 + (tid >> 6);
            int nn = tid & 63;
            Bs[kr][nn] = cw[(size_t)(kc + kr) * D + n0 + nn];
        }
        __syncthreads();
        #pragma unroll
        for (int kk = 0; kk < 32; ++kk) {
            float a[4], bb[4];
            #pragma unroll
            for (int i = 0; i < 4; ++i) a[i] = As[ty * 4 + i][kk];
            #pragma unroll
            for (int j = 0; j < 4; ++j) bb[j] = Bs[kk][tx * 4 + j];
            #pragma unroll
            for (int i = 0; i < 4; ++i)
                #pragma unroll
                for (int j = 0; j < 4; ++j)
                    acc[i][j] = fmaf(a[i], bb[j], acc[i][j]);
        }
        __syncthreads();
    }
    #pragma unroll
    for (int i = 0; i < 4; ++i) {
        int m = m0 + ty * 4 + i;
        int s = m % SEQ;
        int n = n0 + tx * 4;
        float4 v;
        v.x = gelu_exact(acc[i][0]) + pos[(size_t)s * D + n + 0];
        v.y = gelu_exact(acc[i][1]) + pos[(size_t)s * D + n + 1];
        v.z = gelu_exact(acc[i][2]) + pos[(size_t)s * D + n + 2];
        v.w = gelu_exact(acc[i][3]) + pos[(size_t)s * D + n + 3];
        *(float4*)&x[(size_t)m * D + n] = v;
    }
}

// ---------------------------------------------------------------------------
// Kernel 2: per-row mean / rstd (LayerNorm stats). One wave per row.
// ---------------------------------------------------------------------------
__global__ __launch_bounds__(64) void row_stats(
    const float* __restrict__ x, float* __restrict__ st)
{
    const int m = blockIdx.x;
    const int t = threadIdx.x;
    const float* r = x + (size_t)m * D;
    float s = 0.f, q = 0.f;
    #pragma unroll
    for (int i = 0; i < 4; ++i) {
        float v = r[t + 64 * i];
        s += v;
        q += v * v;
    }
    #pragma unroll
    for (int o = 32; o > 0; o >>= 1) {
        s += __shfl_down(s, o);
        q += __shfl_down(q, o);
    }
    if (t == 0) {
        float mu = s * (1.f / 256.f);
        float var = q * (1.f / 256.f) - mu * mu;
        st[2 * m]     = mu;
        st[2 * m + 1] = rsqrtf(var + 1e-5f);
    }
}

// ---------------------------------------------------------------------------
// Kernel 3: fused LN + input-projection GEMM
// ---------------------------------------------------------------------------
__global__ __launch_bounds__(256) void ln_xp_gemm(
    const float* __restrict__ x, const float* __restrict__ st,
    const float* __restrict__ lnsc, const float* __restrict__ lnbi,
    const float* __restrict__ wih, const float* __restrict__ bih,
    float* __restrict__ xp)
{
    __shared__ float As[64][33];
    __shared__ float Bs[32][65];
    __shared__ float sc[D], bi[D];
    const int m0 = blockIdx.x * 64;
    const int n0 = blockIdx.y * 64;
    const int tid = threadIdx.x;
    const int tx = tid & 15;
    const int ty = tid >> 4;
    sc[tid] = lnsc[tid];
    bi[tid] = lnbi[tid];
    float acc[4][4] = {};

    for (int kc = 0; kc < D; kc += 32) {
        for (int p = 0; p < 8; ++p) {
            int mr = p * 8 + (tid >> 5);
            int kk = tid & 31;
            int m = m0 + mr;
            float mu = st[2 * m], rs = st[2 * m + 1];
            float v = x[(size_t)m * D + kc + kk];
            As[mr][kk] = (v - mu) * rs * sc[kc + kk] + bi[kc + kk];
        }
        for (int p = 0; p < 8; ++p) {
            int nr = p * 8 + (tid >> 5);
            int kk = tid & 31;
            Bs[kk][nr] = wih[(size_t)(n0 + nr) * D + kc + kk];
        }
        __syncthreads();
        #pragma unroll
        for (int kk = 0; kk < 32; ++kk) {
            float a[4], bb[4];
            #pragma unroll
            for (int i = 0; i < 4; ++i) a[i] = As[ty * 4 + i][kk];
            #pragma unroll
            for (int j = 0; j < 4; ++j) bb[j] = Bs[kk][tx * 4 + j];
            #pragma unroll
            for (int i = 0; i < 4; ++i)
                #pragma unroll
                for (int j = 0; j < 4; ++j)
                    acc[i][j] = fmaf(a[i], bb[j], acc[i][j]);
        }
        __syncthreads();
    }
    #pragma unroll
    for (int i = 0; i < 4; ++i) {
        int m = m0 + ty * 4 + i;
        int n = n0 + tx * 4;
        float4 v;
        v.x = acc[i][0] + bih[n + 0];
        v.y = acc[i][1] + bih[n + 1];
        v.z = acc[i][2] + bih[n + 2];
        v.w = acc[i][3] + bih[n + 3];
        *(float4*)&xp[(size_t)m * G3 + n] = v;
    }
}

// ---------------------------------------------------------------------------
// Kernel 4: transpose w_hh [768][256] -> whT [256][768]
// ---------------------------------------------------------------------------
__global__ __launch_bounds__(256) void transpose_whh(
    const float* __restrict__ whh, float* __restrict__ whT)
{
    __shared__ float t[32][33];
    const int g0 = blockIdx.x * 32;
    const int k0 = blockIdx.y * 32;
    const int lx = threadIdx.x & 31;
    const int ly = threadIdx.x >> 5;   // 0..7
    for (int i = 0; i < 32; i += 8)
        t[ly + i][lx] = whh[(size_t)(g0 + ly + i) * D + k0 + lx];
    __syncthreads();
    for (int i = 0; i < 32; i += 8)
        whT[(size_t)(k0 + ly + i) * G3 + g0 + lx] = t[lx][ly + i];
}

// ---------------------------------------------------------------------------
// Kernel 4b: zero the exchange buffer (once per launch). Tokens are exact-
// matched per (layer,step), so a zeroed buffer can never alias a live token.
// 32 batches x 2 halves x 2 parities x 384 u64 = 49152 u64.
// ---------------------------------------------------------------------------
__global__ __launch_bounds__(256) void zero_exch(unsigned long long* __restrict__ e)
{
    e[blockIdx.x * 256 + threadIdx.x] = 0ull;
}

// ---------------------------------------------------------------------------
// Kernel 5: GRU recurrence, K-SPLIT pair, register-resident weights.
//
// Round-6 post-mortem: output-split required the peer's h-half before the
// next FMA could start -> the ~2900cy MALL transit sat raw on the chain
// (step 4092cy, publish@1100, pickup@4000). K-split fixes the structure:
//   - block (batch,half) owns W[:, half*128 : half*128+128] (same 192
//     floats/thread) and tracks h[half*128 : +128] -- which IT computes.
//     It never needs peer h. Only peer PARTIAL SUMS are exchanged.
//   - Schedule: FMA-A (partials for PEER's 128 douts, 96 FMA/thr) ->
//     reduce -> PUBLISH at ~600cy (vs 1100). FMA-B (partials for OWN douts)
//     runs DURING the transit. Poll (kq1/2/3, one word each: r/z/n partial
//     for their dd) -> gates -> h_own update, all local.
//   - Chain: publish@600 + transit + gates ~= 2800-3300cy vs 4092.
// Protocol identical in class to proven r1/r2/r6: agent-scope relaxed
// atomics, packed u64 token|payload, parity double-buffer, exact-token
// match. Slot-reuse induction: A overwrites slot(t) at t+2 only after
// consuming peer's t+1, which requires peer finished t, which required
// consuming A's slot(t). Summation order (own-K quarters + peer lump) is
// deterministic and matches round-1's passing re-association.
// ---------------------------------------------------------------------------
__global__ __launch_bounds__(512, 2) void gru_scan_ksplit(
    const float* __restrict__ xp, const float* __restrict__ whT,
    const float* __restrict__ bhh, float* __restrict__ x,
    unsigned long long* exch, int layer)
{
    __shared__ float h_own[128];          // this block's h half
    __shared__ float prA[3][3][128];      // peer-dout partials [kq-1][gate][dd]
    __shared__ float prB[3][3][128];      // own-dout partials
    __shared__ float peerP[3][128];       // received peer partials [gate][dd]
    const int tid  = threadIdx.x;
    const int kq   = tid >> 7;            // 0..3 (wave-uniform: 2 waves/kq)
    const int dd   = tid & 127;
    const int batch = blockIdx.x >> 1;
    const int half  = blockIdx.x & 1;     // K half owned: [128h, 128h+128)
    const int odout = half * 128 + dd;          // own output dim
    const int pdout = (1 - half) * 128 + dd;    // peer-owned output dim
    const int kbase = half * 128 + kq * 32;     // K rows this thread covers

    // --- resident weights: 6 gate-columns x 32 K = 192 floats --------------
    float wpr[32], wpz[32], wpn[32], wor[32], woz[32], won[32];
    {
        const float* wb = whT + (size_t)kbase * G3;
        #pragma unroll
        for (int j = 0; j < 32; ++j) {
            const float* wr_ = wb + (size_t)j * G3;
            wpr[j] = wr_[pdout]; wpz[j] = wr_[D + pdout]; wpn[j] = wr_[2 * D + pdout];
            wor[j] = wr_[odout]; woz[j] = wr_[D + odout]; won[j] = wr_[2 * D + odout];
        }
    }
    const float bh_r = bhh[odout];
    const float bh_z = bhh[D + odout];
    const float bh_n = bhh[2 * D + odout];

    unsigned long long*       pub = exch + (size_t)(batch * 2 + half)       * 2 * 384;
    const unsigned long long* sub = exch + (size_t)(batch * 2 + (1 - half)) * 2 * 384;

    const float* xpb = xp + (size_t)batch * SEQ * G3;
    float* xb = x + (size_t)batch * SEQ * D;

    if (tid < 128) h_own[tid] = 0.f;
    __syncthreads();

    const unsigned int tok0 = (unsigned int)layer * SEQ + 1u;
    for (int t = 0; t < SEQ; ++t) {
        const unsigned int token = tok0 + (unsigned int)t;
        const int par = t & 1;

        // issue xp + residual loads early; latency hides under FMA phases
        float xr = 0.f, xz = 0.f, xn_ = 0.f, xold = 0.f;
        if (kq == 0) {
            const float* xpt = xpb + (size_t)t * G3;
            xr   = xpt[odout];
            xz   = xpt[D + odout];
            xn_  = xpt[2 * D + odout];
            xold = xb[(size_t)t * D + odout];
        }

        // --- phase A: partials for PEER douts over own K quarter -----------
        float ar = 0.f, az = 0.f, an = 0.f;
        {
            const float* hb = &h_own[kq * 32];
            #pragma unroll
            for (int q = 0; q < 8; ++q) {
                float4 hv = *(const float4*)(hb + q * 4);   // uniform bcast
                ar = fmaf(hv.x, wpr[4*q+0], ar); az = fmaf(hv.x, wpz[4*q+0], az); an = fmaf(hv.x, wpn[4*q+0], an);
                ar = fmaf(hv.y, wpr[4*q+1], ar); az = fmaf(hv.y, wpz[4*q+1], az); an = fmaf(hv.y, wpn[4*q+1], an);
                ar = fmaf(hv.z, wpr[4*q+2], ar); az = fmaf(hv.z, wpz[4*q+2], az); an = fmaf(hv.z, wpn[4*q+2], an);
                ar = fmaf(hv.w, wpr[4*q+3], ar); az = fmaf(hv.w, wpz[4*q+3], az); an = fmaf(hv.w, wpn[4*q+3], an);
            }
        }
        if (kq) { prA[kq-1][0][dd] = ar; prA[kq-1][1][dd] = az; prA[kq-1][2][dd] = an; }
        bar_lds();

        // --- kq0: combine + PUBLISH (early; peer pickup is critical path) --
        if (kq == 0) {
            ar += prA[0][0][dd] + prA[1][0][dd] + prA[2][0][dd];
            az += prA[0][1][dd] + prA[1][1][dd] + prA[2][1][dd];
            an += prA[0][2][dd] + prA[1][2][dd] + prA[2][2][dd];
            unsigned long long hi = ((unsigned long long)token << 32);
            unsigned long long* pp = pub + (size_t)par * 384;
            __hip_atomic_store(pp +       dd, hi | __float_as_uint(ar),
                               __ATOMIC_RELAXED, __HIP_MEMORY_SCOPE_AGENT);
            __hip_atomic_store(pp + 128 + dd, hi | __float_as_uint(az),
                               __ATOMIC_RELAXED, __HIP_MEMORY_SCOPE_AGENT);
            __hip_atomic_store(pp + 256 + dd, hi | __float_as_uint(an),
                               __ATOMIC_RELAXED, __HIP_MEMORY_SCOPE_AGENT);
        }

        // --- phase B: partials for OWN douts (overlaps the transit) --------
        float br = 0.f, bz = 0.f, bn = 0.f;
        {
            const float* hb = &h_own[kq * 32];
            #pragma unroll
            for (int q = 0; q < 8; ++q) {
                float4 hv = *(const float4*)(hb + q * 4);
                br = fmaf(hv.x, wor[4*q+0], br); bz = fmaf(hv.x, woz[4*q+0], bz); bn = fmaf(hv.x, won[4*q+0], bn);
                br = fmaf(hv.y, wor[4*q+1], br); bz = fmaf(hv.y, woz[4*q+1], bz); bn = fmaf(hv.y, won[4*q+1], bn);
                br = fmaf(hv.z, wor[4*q+2], br); bz = fmaf(hv.z, woz[4*q+2], bz); bn = fmaf(hv.z, won[4*q+2], bn);
                br = fmaf(hv.w, wor[4*q+3], br); bz = fmaf(hv.w, woz[4*q+3], bz); bn = fmaf(hv.w, won[4*q+3], bn);
            }
        }
        if (kq) { prB[kq-1][0][dd] = br; prB[kq-1][1][dd] = bz; prB[kq-1][2][dd] = bn; }
        bar_lds();

        // --- poll peer partials (kq1/2/3, one word each); kq0 combines own -
        if (kq == 0) {
            br += prB[0][0][dd] + prB[1][0][dd] + prB[2][0][dd];
            bz += prB[0][1][dd] + prB[1][1][dd] + prB[2][1][dd];
            bn += prB[0][2][dd] + prB[1][2][dd] + prB[2][2][dd];
        } else {
            const unsigned long long* qw = sub + (size_t)par * 384 + (kq - 1) * 128 + dd;
            unsigned long long w;
            do {
                w = __hip_atomic_load(qw, __ATOMIC_RELAXED, __HIP_MEMORY_SCOPE_AGENT);
            } while ((unsigned int)(w >> 32) != token);
            peerP[kq - 1][dd] = __uint_as_float((unsigned int)w);
        }
        bar_lds();

        // --- gates + local h update ----------------------------------------
        if (kq == 0) {
            float gr = xr + br + peerP[0][dd] + bh_r;
            float gz = xz + bz + peerP[1][dd] + bh_z;
            float gn =      bn + peerP[2][dd] + bh_n;
            float r = 1.f / (1.f + expf(-gr));
            float z = 1.f / (1.f + expf(-gz));
            float n = tanhf(xn_ + r * gn);
            float hnew = (1.f - z) * n + z * h_own[dd];
            h_own[dd] = hnew;
            xb[(size_t)t * D + odout] = xold + hnew;
        }
        bar_lds();
    }
}

// ---------------------------------------------------------------------------
// Kernel 6: final LN + mean-pool over sequence
// ---------------------------------------------------------------------------
__global__ __launch_bounds__(256) void pool_ln(
    const float* __restrict__ x, const float* __restrict__ st,
    const float* __restrict__ fsc, const float* __restrict__ fbi,
    float* __restrict__ emb)
{
    const int b = blockIdx.x;
    const int d = threadIdx.x;
    float acc = 0.f;
    for (int s = 0; s < SEQ; ++s) {
        int m = b * SEQ + s;
        acc += (x[(size_t)m * D + d] - st[2 * m]) * st[2 * m + 1];
    }
    emb[b * D + d] = (acc * (1.f / (float)SEQ)) * fsc[d] + fbi[d];
}

// ---------------------------------------------------------------------------
// Kernel 7: classification head (tiny). Single block.
// ---------------------------------------------------------------------------
__global__ __launch_bounds__(256) void head_mlp(
    const float* __restrict__ emb, const float* __restrict__ w1,
    const float* __restrict__ b1, const float* __restrict__ w2,
    const float* __restrict__ b2, float* __restrict__ out)
{
    __shared__ float es[NB][D + 1];
    __shared__ float h1[NB][128 + 1];
    const int t = threadIdx.x;
    for (int i = t; i < NB * D; i += 256) es[i / D][i % D] = emb[i];
    __syncthreads();
    for (int i = t; i < NB * 128; i += 256) {
        int bb = i / 128, j = i % 128;
        float a = b1[j];
        for (int k = 0; k < D; ++k) a = fmaf(es[bb][k], w1[(size_t)k * 128 + j], a);
        h1[bb][j] = gelu_exact(a);
    }
    __syncthreads();
    for (int i = t; i < NB * 8; i += 256) {
        int bb = i / 8, c = i % 8;
        float a = b2[c];
        for (int k = 0; k < 128; ++k) a = fmaf(h1[bb][k], w2[(size_t)k * 8 + c], a);
        out[i] = a;
    }
}

// ---------------------------------------------------------------------------
extern "C" void kernel_launch(void* const* d_in, const int* in_sizes, int n_in,
                              void* d_out, int out_size, void* d_ws, size_t ws_size,
                              hipStream_t stream)
{
    const float* wav  = (const float*)d_in[0];
    const float* cw   = (const float*)d_in[1];
    const float* pos  = (const float*)d_in[2];
    const float* lnsc = (const float*)d_in[3];
    const float* lnbi = (const float*)d_in[4];
    const float* wih  = (const float*)d_in[5];
    const float* whh  = (const float*)d_in[6];
    const float* bih  = (const float*)d_in[7];
    const float* bhh  = (const float*)d_in[8];
    const float* fsc  = (const float*)d_in[9];
    const float* fbi  = (const float*)d_in[10];
    const float* hw1  = (const float*)d_in[11];
    const float* hb1  = (const float*)d_in[12];
    const float* hw2  = (const float*)d_in[13];
    const float* hb2  = (const float*)d_in[14];

    float* ws    = (float*)d_ws;
    float* x     = ws;                        // 8,192,000 f
    float* xp    = x + (size_t)M_TOTAL * D;   // 24,576,000 f
    float* st    = xp + (size_t)M_TOTAL * G3; // 64,000 f
    float* whT   = st + 2 * M_TOTAL;          // 196,608 f
    float* emb   = whT + D * G3;              // 8,192 f
    unsigned long long* exch = (unsigned long long*)(emb + NB * D); // 49152 u64

    zero_exch<<<192, 256, 0, stream>>>(exch);  // 49152 u64
    conv_gelu_pos<<<dim3(M_TOTAL / 64, D / 64), 256, 0, stream>>>(wav, cw, pos, x);

    for (int l = 0; l < NL; ++l) {
        row_stats<<<M_TOTAL, 64, 0, stream>>>(x, st);
        ln_xp_gemm<<<dim3(M_TOTAL / 64, G3 / 64), 256, 0, stream>>>(
            x, st, lnsc + (size_t)l * D, lnbi + (size_t)l * D,
            wih + (size_t)l * G3 * D, bih + (size_t)l * G3, xp);
        transpose_whh<<<dim3(G3 / 32, D / 32), 256, 0, stream>>>(
            whh + (size_t)l * G3 * D, whT);
        gru_scan_ksplit<<<NB * 2, 512, 0, stream>>>(
            xp, whT, bhh + (size_t)l * G3, x, exch, l);
    }

    row_stats<<<M_TOTAL, 64, 0, stream>>>(x, st);
    pool_ln<<<NB, D, 0, stream>>>(x, st, fsc, fbi, emb);
    head_mlp<<<1, 256, 0, stream>>>(emb, hw1, hb1, hw2, hb2, (float*)d_out);
}